// Round 6
// baseline (423.640 us; speedup 1.0000x reference)
//
#include <hip/hip_runtime.h>
#include <math.h>

// KGVAE: 2-layer RelGraphConv (bdd) + reparameterize, R17.
// Per-rel MFMA GEMM with FUSED f32 atomicAdd scatter-accumulate (no msg
// materialization, no dst-CSR, no memsets). gemm1f/gemm2f seed the f32
// accumulators with bias+self-loop; gemm_rel adds edge messages atomically;
// dense epilogues finish relu / reparameterize.
// new path ws: embh | w1dT | w2dT | epk(E*16) | h1acc(N*64 f32) | h2acc(N*128 f32)
//              | h1h | bh(R*NB2) | degr | offr
// Fallback: R13 edge path (verified 268.7us) if ws too small or R>256.

typedef __attribute__((ext_vector_type(8))) short bf16x8;
typedef __attribute__((ext_vector_type(4))) float f32x4;
typedef __attribute__((ext_vector_type(2))) _Float16 h2;

__device__ __forceinline__ int bcasti(int v, int l) { return __builtin_amdgcn_readlane(v, l); }
__device__ __forceinline__ float bcastf(float v, int l) {
    return __int_as_float(__builtin_amdgcn_readlane(__float_as_int(v), l));
}
__device__ __forceinline__ unsigned short f2bf(float f) {  // RTN bf16
    unsigned u = __float_as_uint(f);
    return (unsigned short)((u + 0x7FFFu + ((u >> 16) & 1u)) >> 16);
}
__device__ __forceinline__ unsigned short f2h16(float f) {
    return __builtin_bit_cast(unsigned short, (_Float16)f);
}
__device__ __forceinline__ float bfs(unsigned short s) { return __uint_as_float((unsigned)s << 16); }
__device__ __forceinline__ h2 uh2(unsigned u) { return __builtin_bit_cast(h2, u); }

// ---------------- rel-CSR build (no dst CSR needed) ----------------

// 256 edges/block: per-block LDS rel histogram
__global__ __launch_bounds__(256) void
relhist(const int* __restrict__ rel, int* __restrict__ bh, int R, int NB2, int e) {
    __shared__ int h[256];
    int t = threadIdx.x, b = blockIdx.x;
    h[t] = 0;
    __syncthreads();
    int i = b * 256 + t;
    if (i < e) atomicAdd(&h[rel[i]], 1);   // LDS atomic: block-local
    __syncthreads();
    if (t < R) bh[(size_t)t * NB2 + b] = h[t];
}

// one block per rel: exclusive scan of per-block counts -> bases + total
__global__ __launch_bounds__(256) void
rel_scan(int* __restrict__ bh, int* __restrict__ degr, int NB2) {
    __shared__ int sm[256];
    int r = blockIdx.x, t = threadIdx.x;
    int carry = 0;
    for (int s = 0; s < NB2; s += 256) {
        int idx = s + t;
        int v = (idx < NB2) ? bh[(size_t)r * NB2 + idx] : 0;
        sm[t] = v;
        __syncthreads();
        for (int d = 1; d < 256; d <<= 1) {
            int u = (t >= d) ? sm[t - d] : 0;
            __syncthreads();
            sm[t] += u;
            __syncthreads();
        }
        if (idx < NB2) bh[(size_t)r * NB2 + idx] = carry + sm[t] - v;  // exclusive
        int tot = sm[255];
        __syncthreads();
        carry += tot;
    }
    if (t == 0) degr[r] = carry;
}

// single-block exclusive scan over R (<=256) relation counts
__global__ void scan_rel(const int* __restrict__ degr, int* __restrict__ offr, int R) {
    __shared__ int sm[256];
    int t = threadIdx.x;
    int v = (t < R) ? degr[t] : 0;
    sm[t] = v;
    __syncthreads();
    for (int d = 1; d < 256; d <<= 1) {
        int u = (t >= d) ? sm[t - d] : 0;
        __syncthreads();
        sm[t] += u;
        __syncthreads();
    }
    if (t < R) offr[t] = sm[t] - v;
    if (t == 255) offr[R] = sm[255];
}

// rel-order scatter: p = offr[r] + bh[r][b] + lds_rank
// epk[p] = {xidA, xidB, nrm_bits, dst_node}
__global__ __launch_bounds__(256) void
scatterR(const int* __restrict__ src, const int* __restrict__ dst,
         const int* __restrict__ rel, const float* __restrict__ norm,
         const int* __restrict__ h_ids, const int* __restrict__ offr,
         const int* __restrict__ bh, int4* __restrict__ epk, int NB2, int e) {
    __shared__ int h[256];
    int t = threadIdx.x, b = blockIdx.x;
    h[t] = 0;
    __syncthreads();
    int i = b * 256 + t;
    if (i < e) {
        int r = rel[i], s = src[i];
        int lrk = atomicAdd(&h[r], 1);                 // LDS atomic rank
        int p = offr[r] + bh[(size_t)r * NB2 + b] + lrk;
        int4 v;
        v.x = h_ids[s];
        v.y = s;
        v.z = __float_as_int(norm[i]);
        v.w = dst[i];
        epk[p] = v;                                    // one 16B store
    }
}

// ---------------- conversions ----------------

// new path: expand bdd weights to dense TRANSPOSED bf16 [r][outcol][k] + emb->bf16
__global__ void cvt_new(const float* __restrict__ w1, const float* __restrict__ w2,
                        const float* __restrict__ emb, unsigned short* __restrict__ w1dT,
                        unsigned short* __restrict__ w2dT, unsigned short* __restrict__ embh,
                        int R, int ne) {
    int i = blockIdx.x * blockDim.x + threadIdx.x;
    int n1d = R * 4096, n2d = R * 8192;
    if (i < n1d) {
        int r = i >> 12, rem = i & 4095;
        int c = rem >> 6, k = rem & 63;  // c: out col 0..63, k: in 0..63
        int b = k >> 3;
        float v = (b == (c >> 3)) ? w1[(size_t)r * 512 + b * 64 + (k & 7) * 8 + (c & 7)] : 0.f;
        w1dT[i] = f2bf(v);
    } else if (i < n1d + n2d) {
        int ii = i - n1d;
        int r = ii >> 13, rem = ii & 8191;
        int c = rem >> 6, k = rem & 63;  // c: out col 0..127
        int b = k >> 3;
        float v = (b == (c >> 4)) ? w2[(size_t)r * 1024 + b * 128 + (k & 7) * 16 + (c & 15)] : 0.f;
        w2dT[ii] = f2bf(v);
    } else if (i < n1d + n2d + ne) {
        int ii = i - n1d - n2d;
        embh[ii] = f2bf(emb[ii]);
    }
}

// fallback path: w1,w2 -> f16 ; emb -> bf16 (R13)
__global__ void cvt_old(const float* __restrict__ w1, const float* __restrict__ w2,
                        const float* __restrict__ emb, unsigned short* __restrict__ w1h,
                        unsigned short* __restrict__ w2h, unsigned short* __restrict__ embh,
                        int n1, int n2, int ne) {
    int i = blockIdx.x * blockDim.x + threadIdx.x;
    if (i < n1) w1h[i] = f2h16(w1[i]);
    else if (i < n1 + n2) w2h[i - n1] = f2h16(w2[i - n1]);
    else if (i < n1 + n2 + ne) embh[i - n1 - n2] = f2bf(emb[i - n1 - n2]);
}

// ---------------- base GEMMs: seed f32 accumulators with bias + self-loop ----------------

__global__ __launch_bounds__(256) void
gemm1f(const unsigned short* __restrict__ embh, const int* __restrict__ h_ids,
       const float* __restrict__ lw1, const float* __restrict__ b1,
       float* __restrict__ h1acc, int n_nodes) {
    int w = threadIdx.x >> 6, l = threadIdx.x & 63;
    int lr = l & 15, lq = l >> 4;
    int rt = blockIdx.x;
    bf16x8 bfr[2];
    int coln = w * 16 + lr;
#pragma unroll
    for (int kb = 0; kb < 2; ++kb)
#pragma unroll
        for (int jj = 0; jj < 8; ++jj)
            bfr[kb][jj] = (short)f2bf(lw1[(kb * 32 + lq * 8 + jj) * 64 + coln]);
    int nrow = rt * 16 + lr;
    if (nrow >= n_nodes) nrow = n_nodes - 1;
    const unsigned short* arow = embh + (long)h_ids[nrow] * 64 + lq * 8;
    bf16x8 af0 = *(const bf16x8*)arow;
    bf16x8 af1 = *(const bf16x8*)(arow + 32);
    f32x4 acc = {0.f, 0.f, 0.f, 0.f};
    acc = __builtin_amdgcn_mfma_f32_16x16x32_bf16(af0, bfr[0], acc, 0, 0, 0);
    acc = __builtin_amdgcn_mfma_f32_16x16x32_bf16(af1, bfr[1], acc, 0, 0, 0);
    float bb = b1[coln];
#pragma unroll
    for (int r = 0; r < 4; ++r) {
        int row = rt * 16 + lq * 4 + r;
        if (row < n_nodes) h1acc[(long)row * 64 + coln] = acc[r] + bb;
    }
}

__global__ __launch_bounds__(256) void
gemm2f(const unsigned short* __restrict__ h1h, const float* __restrict__ lw2,
       const float* __restrict__ b2, float* __restrict__ h2acc, int n_nodes) {
    int w = threadIdx.x >> 6, l = threadIdx.x & 63;
    int lr = l & 15, lq = l >> 4;
    int rt = blockIdx.x;
    bf16x8 bfr[2][2];
    int col0 = (2 * w) * 16 + lr, col1 = (2 * w + 1) * 16 + lr;
#pragma unroll
    for (int kb = 0; kb < 2; ++kb)
#pragma unroll
        for (int jj = 0; jj < 8; ++jj) {
            int k = kb * 32 + lq * 8 + jj;
            bfr[0][kb][jj] = (short)f2bf(lw2[k * 128 + col0]);
            bfr[1][kb][jj] = (short)f2bf(lw2[k * 128 + col1]);
        }
    int nrow = rt * 16 + lr;
    if (nrow >= n_nodes) nrow = n_nodes - 1;
    bf16x8 af0 = *(const bf16x8*)(h1h + (long)nrow * 64 + lq * 8);
    bf16x8 af1 = *(const bf16x8*)(h1h + (long)nrow * 64 + 32 + lq * 8);
    f32x4 acc0 = {0.f, 0.f, 0.f, 0.f}, acc1 = {0.f, 0.f, 0.f, 0.f};
    acc0 = __builtin_amdgcn_mfma_f32_16x16x32_bf16(af0, bfr[0][0], acc0, 0, 0, 0);
    acc0 = __builtin_amdgcn_mfma_f32_16x16x32_bf16(af1, bfr[0][1], acc0, 0, 0, 0);
    acc1 = __builtin_amdgcn_mfma_f32_16x16x32_bf16(af0, bfr[1][0], acc1, 0, 0, 0);
    acc1 = __builtin_amdgcn_mfma_f32_16x16x32_bf16(af1, bfr[1][1], acc1, 0, 0, 0);
    float bb0 = b2[col0], bb1 = b2[col1];
#pragma unroll
    for (int r = 0; r < 4; ++r) {
        int row = rt * 16 + lq * 4 + r;
        if (row < n_nodes) {
            h2acc[(long)row * 128 + col0] = acc0[r] + bb0;
            h2acc[(long)row * 128 + col1] = acc1[r] + bb1;
        }
    }
}

// ---------------- per-rel message GEMMs with fused atomic scatter-add ----------------

// h1acc[dst][64] += (embh[xidA] @ W1d_r) * nrm   (f32 atomics)
__global__ __launch_bounds__(256) void
gemm_rel1(const unsigned short* __restrict__ embh, const unsigned short* __restrict__ w1dT,
          const int4* __restrict__ epk, const int* __restrict__ offr,
          float* __restrict__ h1acc, int S) {
    int r = blockIdx.x / S, s = blockIdx.x % S;
    int w = threadIdx.x >> 6, l = threadIdx.x & 63;
    int lr = l & 15, lq = l >> 4;
    int e0r = offr[r], e1r = offr[r + 1];
    if (e0r >= e1r) return;
    bf16x8 bfr[4][2];
    const unsigned short* wb = w1dT + (size_t)r * 4096;
#pragma unroll
    for (int ct = 0; ct < 4; ++ct)
#pragma unroll
        for (int kb = 0; kb < 2; ++kb)
            bfr[ct][kb] = *(const bf16x8*)(wb + (ct * 16 + lr) * 64 + kb * 32 + lq * 8);
    for (int t = s * 4 + w;; t += S * 4) {
        int t16 = e0r + t * 16;
        if (t16 >= e1r) break;
        int erow = t16 + lr;
        int erc = erow < e1r ? erow : e1r - 1;
        int xa = epk[erc].x;
        const unsigned short* arow = embh + (size_t)xa * 64 + lq * 8;
        bf16x8 af0 = *(const bf16x8*)arow;
        bf16x8 af1 = *(const bf16x8*)(arow + 32);
        f32x4 acc[4];
#pragma unroll
        for (int ct = 0; ct < 4; ++ct) {
            acc[ct] = (f32x4){0.f, 0.f, 0.f, 0.f};
            acc[ct] = __builtin_amdgcn_mfma_f32_16x16x32_bf16(af0, bfr[ct][0], acc[ct], 0, 0, 0);
            acc[ct] = __builtin_amdgcn_mfma_f32_16x16x32_bf16(af1, bfr[ct][1], acc[ct], 0, 0, 0);
        }
#pragma unroll
        for (int r4 = 0; r4 < 4; ++r4) {
            int orow = t16 + lq * 4 + r4;
            if (orow < e1r) {
                int2 nq = *(const int2*)(&epk[orow].z);     // {nrm_bits, dst}
                float nm = __int_as_float(nq.x);
                size_t dn = (size_t)nq.y;
#pragma unroll
                for (int ct = 0; ct < 4; ++ct)
                    atomicAdd(&h1acc[dn * 64 + ct * 16 + lr], acc[ct][r4] * nm);
            }
        }
    }
}

// h2acc[dst][128] += (h1h[xidB] @ W2d_r) * nrm   (f32 atomics)
__global__ __launch_bounds__(256) void
gemm_rel2(const unsigned short* __restrict__ h1h, const unsigned short* __restrict__ w2dT,
          const int4* __restrict__ epk, const int* __restrict__ offr,
          float* __restrict__ h2acc, int S) {
    int r = blockIdx.x / S, s = blockIdx.x % S;
    int w = threadIdx.x >> 6, l = threadIdx.x & 63;
    int lr = l & 15, lq = l >> 4;
    int e0r = offr[r], e1r = offr[r + 1];
    if (e0r >= e1r) return;
    bf16x8 bfr[8][2];
    const unsigned short* wb = w2dT + (size_t)r * 8192;
#pragma unroll
    for (int ct = 0; ct < 8; ++ct)
#pragma unroll
        for (int kb = 0; kb < 2; ++kb)
            bfr[ct][kb] = *(const bf16x8*)(wb + (ct * 16 + lr) * 64 + kb * 32 + lq * 8);
    for (int t = s * 4 + w;; t += S * 4) {
        int t16 = e0r + t * 16;
        if (t16 >= e1r) break;
        int erow = t16 + lr;
        int erc = erow < e1r ? erow : e1r - 1;
        int xb = epk[erc].y;
        const unsigned short* arow = h1h + (size_t)xb * 64 + lq * 8;
        bf16x8 af0 = *(const bf16x8*)arow;
        bf16x8 af1 = *(const bf16x8*)(arow + 32);
        f32x4 acc[8];
#pragma unroll
        for (int ct = 0; ct < 8; ++ct) {
            acc[ct] = (f32x4){0.f, 0.f, 0.f, 0.f};
            acc[ct] = __builtin_amdgcn_mfma_f32_16x16x32_bf16(af0, bfr[ct][0], acc[ct], 0, 0, 0);
            acc[ct] = __builtin_amdgcn_mfma_f32_16x16x32_bf16(af1, bfr[ct][1], acc[ct], 0, 0, 0);
        }
#pragma unroll
        for (int r4 = 0; r4 < 4; ++r4) {
            int orow = t16 + lq * 4 + r4;
            if (orow < e1r) {
                int2 nq = *(const int2*)(&epk[orow].z);
                float nm = __int_as_float(nq.x);
                size_t dn = (size_t)nq.y;
#pragma unroll
                for (int ct = 0; ct < 8; ++ct)
                    atomicAdd(&h2acc[dn * 128 + ct * 16 + lr], acc[ct][r4] * nm);
            }
        }
    }
}

// ---------------- dense epilogues ----------------

// h1h = bf16(relu(h1acc))
__global__ __launch_bounds__(256) void
ep1(const float* __restrict__ h1acc, unsigned short* __restrict__ h1h, int total) {
    int i = blockIdx.x * blockDim.x + threadIdx.x;
    if (i < total) h1h[i] = f2bf(fmaxf(h1acc[i], 0.f));
}

// out = reparam(h2acc)
__global__ __launch_bounds__(256) void
ep2(const float* __restrict__ h2acc, const float* __restrict__ eps,
    float* __restrict__ out, int total) {
    int i = blockIdx.x * blockDim.x + threadIdx.x;
    if (i >= total) return;
    int n = i >> 6, j = i & 63;
    float vm = h2acc[(size_t)n * 128 + j];
    float vv = h2acc[(size_t)n * 128 + 64 + j];
    float sp = (vv > 20.f) ? vv : log1pf(expf(vv));
    out[i] = fmaf(sqrtf(sp + 1e-8f), eps[i], vm);
}

// ---------------- R13 fallback edge path (verified) ----------------

__global__ void hist2(const int* __restrict__ dst, const int* __restrict__ rel,
                      int* __restrict__ deg, int* __restrict__ degr, int e) {
    int i = blockIdx.x * blockDim.x + threadIdx.x;
    if (i < e) {
        atomicAdd(&deg[dst[i]], 1);
        atomicAdd(&degr[rel[i]], 1);
    }
}

__global__ void scan_part(const int* __restrict__ deg, int* __restrict__ bsum, int n) {
    __shared__ int sm[256];
    int t = threadIdx.x, g = blockIdx.x * 256 + t;
    sm[t] = (g < n) ? deg[g] : 0;
    __syncthreads();
    for (int d = 128; d > 0; d >>= 1) {
        if (t < d) sm[t] += sm[t + d];
        __syncthreads();
    }
    if (t == 0) bsum[blockIdx.x] = sm[0];
}

__global__ void scan_bsum(int* __restrict__ bsum, int* __restrict__ off, int nb, int n) {
    __shared__ int sm[256];
    int t = threadIdx.x;
    int v = (t < nb) ? bsum[t] : 0;
    sm[t] = v;
    __syncthreads();
    for (int d = 1; d < 256; d <<= 1) {
        int u = (t >= d) ? sm[t - d] : 0;
        __syncthreads();
        sm[t] += u;
        __syncthreads();
    }
    if (t < nb) bsum[t] = sm[t] - v;
    if (t == 255) off[n] = sm[255];
}

__global__ void scan_write(const int* __restrict__ deg, const int* __restrict__ bsum,
                           int* __restrict__ off, int n) {
    __shared__ int sm[256];
    int t = threadIdx.x, g = blockIdx.x * 256 + t;
    int v = (g < n) ? deg[g] : 0;
    sm[t] = v;
    __syncthreads();
    for (int d = 1; d < 256; d <<= 1) {
        int u = (t >= d) ? sm[t - d] : 0;
        __syncthreads();
        sm[t] += u;
        __syncthreads();
    }
    if (g < n) off[g] = bsum[blockIdx.x] + sm[t] - v;
}

__global__ void scatter_pack(const int* __restrict__ src, const int* __restrict__ dst,
                             const int* __restrict__ rel, const float* __restrict__ norm,
                             const int* __restrict__ h_ids, const int* __restrict__ off,
                             int* __restrict__ fil, unsigned* __restrict__ packA,
                             unsigned* __restrict__ packB, float* __restrict__ norm_s, int e) {
    int i = blockIdx.x * blockDim.x + threadIdx.x;
    if (i >= e) return;
    int d = dst[i];
    int p = off[d] + atomicAdd(&fil[d], 1);
    unsigned rhi = (unsigned)rel[i] << 16;
    int s = src[i];
    packA[p] = (unsigned)h_ids[s] | rhi;
    packB[p] = (unsigned)s | rhi;
    norm_s[p] = norm[i];
}

__device__ __forceinline__ float reduce8(float a0, float a1, float a2, float a3,
                                         float a4, float a5, float a6, float a7, int i) {
    int p1 = i & 1, p2 = (i >> 1) & 1, p3 = (i >> 2) & 1;
    float ka, sb, u0, u1, u2, u3, w0, w1;
    ka = p1 ? a1 : a0; sb = p1 ? a0 : a1; u0 = ka + __shfl_xor(sb, 1, 64);
    ka = p1 ? a3 : a2; sb = p1 ? a2 : a3; u1 = ka + __shfl_xor(sb, 1, 64);
    ka = p1 ? a5 : a4; sb = p1 ? a4 : a5; u2 = ka + __shfl_xor(sb, 1, 64);
    ka = p1 ? a7 : a6; sb = p1 ? a6 : a7; u3 = ka + __shfl_xor(sb, 1, 64);
    ka = p2 ? u1 : u0; sb = p2 ? u0 : u1; w0 = ka + __shfl_xor(sb, 2, 64);
    ka = p2 ? u3 : u2; sb = p2 ? u2 : u3; w1 = ka + __shfl_xor(sb, 2, 64);
    ka = p3 ? w1 : w0; sb = p3 ? w0 : w1;
    return ka + __shfl_xor(sb, 4, 64);
}

__global__ __launch_bounds__(256) void
gemm1_mfma(const unsigned short* __restrict__ embh, const int* __restrict__ h_ids,
           const float* __restrict__ lw1, const float* __restrict__ b1,
           unsigned short* __restrict__ h1bh, int n_nodes) {
    int w = threadIdx.x >> 6, l = threadIdx.x & 63;
    int lr = l & 15, lq = l >> 4;
    int rt = blockIdx.x;
    bf16x8 bfr[2];
    int coln = w * 16 + lr;
#pragma unroll
    for (int kb = 0; kb < 2; ++kb)
#pragma unroll
        for (int jj = 0; jj < 8; ++jj)
            bfr[kb][jj] = (short)f2bf(lw1[(kb * 32 + lq * 8 + jj) * 64 + coln]);
    int nrow = rt * 16 + lr;
    if (nrow >= n_nodes) nrow = n_nodes - 1;
    const unsigned short* arow = embh + (long)h_ids[nrow] * 64 + lq * 8;
    bf16x8 af0 = *(const bf16x8*)arow;
    bf16x8 af1 = *(const bf16x8*)(arow + 32);
    f32x4 acc = {0.f, 0.f, 0.f, 0.f};
    acc = __builtin_amdgcn_mfma_f32_16x16x32_bf16(af0, bfr[0], acc, 0, 0, 0);
    acc = __builtin_amdgcn_mfma_f32_16x16x32_bf16(af1, bfr[1], acc, 0, 0, 0);
    float bb = b1[coln];
#pragma unroll
    for (int r = 0; r < 4; ++r) {
        int row = rt * 16 + lq * 4 + r;
        if (row < n_nodes) h1bh[(long)row * 64 + coln] = f2bf(acc[r] + bb);
    }
}

__global__ __launch_bounds__(256) void
gemm2_mfma(const unsigned short* __restrict__ h1h, const float* __restrict__ lw2,
           const float* __restrict__ b2, unsigned short* __restrict__ h2bh, int n_nodes) {
    int w = threadIdx.x >> 6, l = threadIdx.x & 63;
    int lr = l & 15, lq = l >> 4;
    int rt = blockIdx.x;
    bf16x8 bfr[2][2];
    int col0 = (2 * w) * 16 + lr, col1 = (2 * w + 1) * 16 + lr;
#pragma unroll
    for (int kb = 0; kb < 2; ++kb)
#pragma unroll
        for (int jj = 0; jj < 8; ++jj) {
            int k = kb * 32 + lq * 8 + jj;
            bfr[0][kb][jj] = (short)f2bf(lw2[k * 128 + col0]);
            bfr[1][kb][jj] = (short)f2bf(lw2[k * 128 + col1]);
        }
    int nrow = rt * 16 + lr;
    if (nrow >= n_nodes) nrow = n_nodes - 1;
    bf16x8 af0 = *(const bf16x8*)(h1h + (long)nrow * 64 + lq * 8);
    bf16x8 af1 = *(const bf16x8*)(h1h + (long)nrow * 64 + 32 + lq * 8);
    f32x4 acc0 = {0.f, 0.f, 0.f, 0.f}, acc1 = {0.f, 0.f, 0.f, 0.f};
    acc0 = __builtin_amdgcn_mfma_f32_16x16x32_bf16(af0, bfr[0][0], acc0, 0, 0, 0);
    acc0 = __builtin_amdgcn_mfma_f32_16x16x32_bf16(af1, bfr[0][1], acc0, 0, 0, 0);
    acc1 = __builtin_amdgcn_mfma_f32_16x16x32_bf16(af0, bfr[1][0], acc1, 0, 0, 0);
    acc1 = __builtin_amdgcn_mfma_f32_16x16x32_bf16(af1, bfr[1][1], acc1, 0, 0, 0);
    float bb0 = b2[col0], bb1 = b2[col1];
#pragma unroll
    for (int r = 0; r < 4; ++r) {
        int row = rt * 16 + lq * 4 + r;
        if (row < n_nodes) {
            h2bh[(long)row * 128 + col0] = f2bf(acc0[r] + bb0);
            h2bh[(long)row * 128 + col1] = f2bf(acc1[r] + bb1);
        }
    }
}

__global__ __launch_bounds__(256) void
edge1(const unsigned short* __restrict__ embh, const unsigned short* __restrict__ w1h,
      const unsigned short* __restrict__ h1bh, const int* __restrict__ off,
      const unsigned* __restrict__ packA, const float* __restrict__ norm_s,
      unsigned short* __restrict__ h1h, int n_nodes) {
    __shared__ unsigned short xstage[4][8][64];
    int tid = threadIdx.x;
    int w = tid >> 6, j = tid & 63, i = j & 7;
    int cl = j >> 3, il = j & 7;
    int n = blockIdx.x * 4 + w;
    if (n >= n_nodes) return;
    unsigned short* xsw = &xstage[w][0][0];
    float base = bfs(h1bh[(long)n * 64 + j]);
    h2 acc[4];
#pragma unroll
    for (int q = 0; q < 4; ++q) acc[q] = (h2){(_Float16)0.f, (_Float16)0.f};
    int e0 = off[n], e1v = off[n + 1];
    const long woff = (long)j * 8;
    for (int win = e0; win < e1v; win += 64) {
        int wcnt = e1v - win; if (wcnt > 64) wcnt = 64;
        unsigned u = (j < wcnt) ? packA[win + j] : 0u;
        float nmv = (j < wcnt) ? norm_s[win + j] : 0.f;
        for (int b8 = 0; b8 < wcnt; b8 += 8) {
            int cnt = wcnt - b8; if (cnt > 8) cnt = 8;
            int uc = __builtin_amdgcn_ds_bpermute((b8 + cl) << 2, (int)u);
            if (cl < cnt)
                *(bf16x8*)(xsw + (cl << 6) + (il << 3)) =
                    *(const bf16x8*)(embh + (long)((unsigned)uc & 0xFFFFu) * 64 + (il << 3));
            asm volatile("s_waitcnt lgkmcnt(0)" ::: "memory");
#pragma unroll
            for (int c = 0; c < 8; ++c)
                if (c < cnt) {
                    float nm = bcastf(nmv, b8 + c);
                    int rr = bcasti((int)u, b8 + c) >> 16;
                    uint4 wd = *(const uint4*)(w1h + (long)rr * 512 + woff);
                    _Float16 xh = (_Float16)(bfs(xsw[(c << 6) + j]) * nm);
                    h2 xh2 = {xh, xh};
                    acc[0] += xh2 * uh2(wd.x);
                    acc[1] += xh2 * uh2(wd.y);
                    acc[2] += xh2 * uh2(wd.z);
                    acc[3] += xh2 * uh2(wd.w);
                }
        }
    }
    float agg = reduce8((float)acc[0].x, (float)acc[0].y, (float)acc[1].x, (float)acc[1].y,
                        (float)acc[2].x, (float)acc[2].y, (float)acc[3].x, (float)acc[3].y, i);
    h1h[(long)n * 64 + j] = f2bf(fmaxf(base + agg, 0.f));
}

__global__ __launch_bounds__(256) void
edge2(const unsigned short* __restrict__ h1h, const unsigned short* __restrict__ w2h,
      const unsigned short* __restrict__ h2bh, const float* __restrict__ eps,
      const int* __restrict__ off, const unsigned* __restrict__ packB,
      const float* __restrict__ norm_s, float* __restrict__ out, int n_nodes) {
    __shared__ unsigned short xstage[4][8][64];
    int tid = threadIdx.x;
    int w = tid >> 6, j = tid & 63;
    int i = j & 7, b = j >> 3;
    int o1 = b * 16 + i, o2 = o1 + 8;
    int cl = j >> 3, il = j & 7;
    int n = blockIdx.x * 4 + w;
    if (n >= n_nodes) return;
    unsigned short* xsw = &xstage[w][0][0];
    float base1 = bfs(h2bh[(long)n * 128 + o1]);
    float base2 = bfs(h2bh[(long)n * 128 + o2]);
    h2 acc[8];
#pragma unroll
    for (int q = 0; q < 8; ++q) acc[q] = (h2){(_Float16)0.f, (_Float16)0.f};
    int e0 = off[n], e1v = off[n + 1];
    const long woff = (long)j * 16;
    for (int win = e0; win < e1v; win += 64) {
        int wcnt = e1v - win; if (wcnt > 64) wcnt = 64;
        unsigned u = (j < wcnt) ? packB[win + j] : 0u;
        float nmv = (j < wcnt) ? norm_s[win + j] : 0.f;
        for (int b8 = 0; b8 < wcnt; b8 += 8) {
            int cnt = wcnt - b8; if (cnt > 8) cnt = 8;
            int uc = __builtin_amdgcn_ds_bpermute((b8 + cl) << 2, (int)u);
            if (cl < cnt)
                *(bf16x8*)(xsw + (cl << 6) + (il << 3)) =
                    *(const bf16x8*)(h1h + (long)((unsigned)uc & 0xFFFFu) * 64 + (il << 3));
            asm volatile("s_waitcnt lgkmcnt(0)" ::: "memory");
#pragma unroll
            for (int c = 0; c < 8; ++c)
                if (c < cnt) {
                    float nm = bcastf(nmv, b8 + c);
                    int rr = bcasti((int)u, b8 + c) >> 16;
                    const uint4* p = (const uint4*)(w2h + (long)rr * 1024 + woff);
                    uint4 wa = p[0], wb = p[1];
                    _Float16 xh = (_Float16)(bfs(xsw[(c << 6) + j]) * nm);
                    h2 xh2 = {xh, xh};
                    acc[0] += xh2 * uh2(wa.x);
                    acc[1] += xh2 * uh2(wa.y);
                    acc[2] += xh2 * uh2(wa.z);
                    acc[3] += xh2 * uh2(wa.w);
                    acc[4] += xh2 * uh2(wb.x);
                    acc[5] += xh2 * uh2(wb.y);
                    acc[6] += xh2 * uh2(wb.z);
                    acc[7] += xh2 * uh2(wb.w);
                }
        }
    }
    float r1 = reduce8((float)acc[0].x, (float)acc[0].y, (float)acc[1].x, (float)acc[1].y,
                       (float)acc[2].x, (float)acc[2].y, (float)acc[3].x, (float)acc[3].y, i);
    float r2 = reduce8((float)acc[4].x, (float)acc[4].y, (float)acc[5].x, (float)acc[5].y,
                       (float)acc[6].x, (float)acc[6].y, (float)acc[7].x, (float)acc[7].y, i);
    float v1 = r1 + base1;
    float v2 = r2 + base2;
    float p1 = __shfl_xor(v1, 32, 64);
    float p2 = __shfl_xor(v2, 32, 64);
    if (j < 32) {
        long basep = (long)n * 64;
        float sp1 = (p1 > 20.f) ? p1 : log1pf(expf(p1));
        float sp2 = (p2 > 20.f) ? p2 : log1pf(expf(p2));
        out[basep + o1] = fmaf(sqrtf(sp1 + 1e-8f), eps[basep + o1], v1);
        out[basep + o2] = fmaf(sqrtf(sp2 + 1e-8f), eps[basep + o2], v2);
    }
}

// ---------------- host ----------------

extern "C" void kernel_launch(void* const* d_in, const int* in_sizes, int n_in,
                              void* d_out, int out_size, void* d_ws, size_t ws_size,
                              hipStream_t stream) {
    const float* emb   = (const float*)d_in[0];
    const float* norm  = (const float*)d_in[1];
    const float* eps   = (const float*)d_in[2];
    const float* w1    = (const float*)d_in[3];
    const float* lw1   = (const float*)d_in[4];
    const float* b1    = (const float*)d_in[5];
    const float* w2    = (const float*)d_in[6];
    const float* lw2   = (const float*)d_in[7];
    const float* b2    = (const float*)d_in[8];
    const int*   h_ids = (const int*)d_in[9];
    const int*   src   = (const int*)d_in[10];
    const int*   dst   = (const int*)d_in[11];
    const int*   rel   = (const int*)d_in[12];
    float* out = (float*)d_out;

    int n_nodes = in_sizes[0] / 64;   // 50000
    int n_edges = in_sizes[10];       // 400000
    int nw1 = in_sizes[3];            // R*512
    int nw2 = in_sizes[6];            // R*1024
    int ne  = in_sizes[0];            // N*64
    int R   = nw1 / 512;              // 200

    int blk = 256;
    int nb = (n_nodes + 255) / 256;
    int nt = (n_nodes + 15) / 16;
    int NB2 = (n_edges + 255) / 256;  // 256 edges per build block

    // new-path workspace requirement
    size_t need = (size_t)ne * 2                       // embh
                + (size_t)R * 4096 * 2                 // w1dT
                + (size_t)R * 8192 * 2                 // w2dT
                + (size_t)n_edges * 16                 // epk
                + (size_t)n_nodes * 64 * 4             // h1acc
                + (size_t)n_nodes * 128 * 4            // h2acc
                + (size_t)n_nodes * 64 * 2             // h1h
                + (size_t)R * NB2 * 4                  // bh
                + (size_t)R * 4                        // degr
                + (size_t)(R + 1) * 4;                 // offr

    if (ws_size >= need && R <= 256) {
        char* p = (char*)d_ws;
        unsigned short* embh = (unsigned short*)p;  p += (size_t)ne * 2;
        unsigned short* w1dT = (unsigned short*)p;  p += (size_t)R * 4096 * 2;
        unsigned short* w2dT = (unsigned short*)p;  p += (size_t)R * 8192 * 2;
        int4*  epk = (int4*)p;                      p += (size_t)n_edges * 16;
        float* h1acc = (float*)p;                   p += (size_t)n_nodes * 64 * 4;
        float* h2acc = (float*)p;                   p += (size_t)n_nodes * 128 * 4;
        unsigned short* h1h = (unsigned short*)p;   p += (size_t)n_nodes * 64 * 2;
        int* bh   = (int*)p;                        p += (size_t)R * NB2 * 4;
        int* degr = (int*)p;                        p += (size_t)R * 4;
        int* offr = (int*)p;

        const int S = 16;
        int ncv = R * 4096 + R * 8192 + ne;
        cvt_new<<<(ncv + blk - 1) / blk, blk, 0, stream>>>(w1, w2, emb, w1dT, w2dT, embh, R, ne);
        relhist<<<NB2, blk, 0, stream>>>(rel, bh, R, NB2, n_edges);
        rel_scan<<<R, 256, 0, stream>>>(bh, degr, NB2);
        scan_rel<<<1, 256, 0, stream>>>(degr, offr, R);
        scatterR<<<NB2, blk, 0, stream>>>(src, dst, rel, norm, h_ids, offr, bh, epk, NB2, n_edges);
        // layer 1: seed base, atomic-accumulate messages, relu
        gemm1f<<<nt, blk, 0, stream>>>(embh, h_ids, lw1, b1, h1acc, n_nodes);
        gemm_rel1<<<R * S, blk, 0, stream>>>(embh, w1dT, epk, offr, h1acc, S);
        ep1<<<(n_nodes * 64 + blk - 1) / blk, blk, 0, stream>>>(h1acc, h1h, n_nodes * 64);
        // layer 2
        gemm2f<<<nt, blk, 0, stream>>>(h1h, lw2, b2, h2acc, n_nodes);
        gemm_rel2<<<R * S, blk, 0, stream>>>(h1h, w2dT, epk, offr, h2acc, S);
        ep2<<<(n_nodes * 64 + blk - 1) / blk, blk, 0, stream>>>(h2acc, eps, out, n_nodes * 64);
    } else {
        // R13 fallback
        int ng = (n_nodes + 3) / 4;
        char* p = (char*)d_ws;
        unsigned short* h1bh = (unsigned short*)p;  p += (size_t)n_nodes * 64 * 2;
        unsigned short* h1h  = (unsigned short*)p;  p += (size_t)n_nodes * 64 * 2;
        unsigned short* h2bh = (unsigned short*)p;  p += (size_t)n_nodes * 128 * 2;
        unsigned short* embh = (unsigned short*)p;  p += (size_t)ne * 2;
        unsigned short* w1h  = (unsigned short*)p;  p += (size_t)nw1 * 2;
        unsigned short* w2h  = (unsigned short*)p;  p += (size_t)nw2 * 2;
        unsigned* pkA = (unsigned*)p;               p += (size_t)n_edges * 4;
        unsigned* pkB = (unsigned*)p;               p += (size_t)n_edges * 4;
        float* norm_s = (float*)p;                  p += (size_t)n_edges * 4;
        int* deg  = (int*)p;                        p += (size_t)n_nodes * 4;
        int* fil  = (int*)p;                        p += (size_t)n_nodes * 4;
        int* degr = (int*)p;                        p += (size_t)R * 4;
        int* filr = (int*)p;                        p += (size_t)R * 4;
        int* off  = (int*)p;                        p += (size_t)(n_nodes + 1) * 4;
        int* bsum = (int*)p;

        hipMemsetAsync(deg, 0, (size_t)(2 * n_nodes + 2 * R) * 4, stream);
        cvt_old<<<(nw1 + nw2 + ne + blk - 1) / blk, blk, 0, stream>>>(w1, w2, emb, w1h, w2h, embh, nw1, nw2, ne);
        hist2<<<(n_edges + blk - 1) / blk, blk, 0, stream>>>(dst, rel, deg, degr, n_edges);
        scan_part<<<nb, 256, 0, stream>>>(deg, bsum, n_nodes);
        scan_bsum<<<1, 256, 0, stream>>>(bsum, off, nb, n_nodes);
        scan_write<<<nb, 256, 0, stream>>>(deg, bsum, off, n_nodes);
        scatter_pack<<<(n_edges + blk - 1) / blk, blk, 0, stream>>>(
            src, dst, rel, norm, h_ids, off, fil, pkA, pkB, norm_s, n_edges);
        gemm1_mfma<<<nt, blk, 0, stream>>>(embh, h_ids, lw1, b1, h1bh, n_nodes);
        edge1<<<ng, blk, 0, stream>>>(embh, w1h, h1bh, off, pkA, norm_s, h1h, n_nodes);
        gemm2_mfma<<<nt, blk, 0, stream>>>(h1h, lw2, b2, h2bh, n_nodes);
        edge2<<<ng, blk, 0, stream>>>(h1h, w2h, h2bh, eps, off, pkB, norm_s, out, n_nodes);
    }
}

// Round 8
// 263.407 us; speedup vs baseline: 1.6083x; 1.6083x over previous
//
#include <hip/hip_runtime.h>
#include <math.h>

// KGVAE: 2-layer RelGraphConv (bdd) + reparameterize, R18b (R18 resubmit;
// previous round was a container-infra failure, kernel never ran).
// = R13 (best verified, 268.7us: dst-CSR edge walk, 1 node/wave, LDS bulk
//   gather, f16 packed-FMA edge math, MFMA self-loop GEMMs)
// + global_load_lds (width=16) staging: gather goes HBM->LDS directly
//   (one instr, wave-uniform LDS base + lane*16B, per-lane global addr),
//   replacing global->VGPR->ds_write and its two dependent waits.
// ws: h1bh | h1h | h2bh | embh | w1h(f16) | w2h(f16) | pkA | pkB | norm_s
//     | deg fil | off | bsum

typedef __attribute__((ext_vector_type(8))) short bf16x8;
typedef __attribute__((ext_vector_type(4))) float f32x4;
typedef __attribute__((ext_vector_type(2))) _Float16 h2;

__device__ __forceinline__ int bcasti(int v, int l) { return __builtin_amdgcn_readlane(v, l); }
__device__ __forceinline__ float bcastf(float v, int l) {
    return __int_as_float(__builtin_amdgcn_readlane(__float_as_int(v), l));
}
__device__ __forceinline__ unsigned short f2bf(float f) {  // RTN bf16
    unsigned u = __float_as_uint(f);
    return (unsigned short)((u + 0x7FFFu + ((u >> 16) & 1u)) >> 16);
}
__device__ __forceinline__ unsigned short f2h(float f) {   // RN f16
    return __builtin_bit_cast(unsigned short, (_Float16)f);
}
__device__ __forceinline__ float bfs(unsigned short s) { return __uint_as_float((unsigned)s << 16); }
__device__ __forceinline__ h2 uh2(unsigned u) { return __builtin_bit_cast(h2, u); }

// direct global->LDS 16B: LDS dest = base + lane*16 (HW), global addr per-lane
__device__ __forceinline__ void gload_lds16(const void* g, void* l) {
    __builtin_amdgcn_global_load_lds(
        (const __attribute__((address_space(1))) unsigned int*)g,
        (__attribute__((address_space(3))) unsigned int*)l, 16, 0, 0);
}

__global__ void hist(const int* __restrict__ dst, int* __restrict__ deg, int e) {
    int i = blockIdx.x * blockDim.x + threadIdx.x;
    if (i < e) atomicAdd(&deg[dst[i]], 1);
}

__global__ void scan_part(const int* __restrict__ deg, int* __restrict__ bsum, int n) {
    __shared__ int sm[256];
    int t = threadIdx.x, g = blockIdx.x * 256 + t;
    sm[t] = (g < n) ? deg[g] : 0;
    __syncthreads();
    for (int d = 128; d > 0; d >>= 1) {
        if (t < d) sm[t] += sm[t + d];
        __syncthreads();
    }
    if (t == 0) bsum[blockIdx.x] = sm[0];
}

__global__ void scan_bsum(int* __restrict__ bsum, int* __restrict__ off, int nb, int n) {
    __shared__ int sm[256];
    int t = threadIdx.x;
    int v = (t < nb) ? bsum[t] : 0;
    sm[t] = v;
    __syncthreads();
    for (int d = 1; d < 256; d <<= 1) {
        int u = (t >= d) ? sm[t - d] : 0;
        __syncthreads();
        sm[t] += u;
        __syncthreads();
    }
    if (t < nb) bsum[t] = sm[t] - v;
    if (t == 255) off[n] = sm[255];
}

__global__ void scan_write(const int* __restrict__ deg, const int* __restrict__ bsum,
                           int* __restrict__ off, int n) {
    __shared__ int sm[256];
    int t = threadIdx.x, g = blockIdx.x * 256 + t;
    int v = (g < n) ? deg[g] : 0;
    sm[t] = v;
    __syncthreads();
    for (int d = 1; d < 256; d <<= 1) {
        int u = (t >= d) ? sm[t - d] : 0;
        __syncthreads();
        sm[t] += u;
        __syncthreads();
    }
    if (g < n) off[g] = bsum[blockIdx.x] + sm[t] - v;
}

__global__ void scatter_pack(const int* __restrict__ src, const int* __restrict__ dst,
                             const int* __restrict__ rel, const float* __restrict__ norm,
                             const int* __restrict__ h_ids, const int* __restrict__ off,
                             int* __restrict__ fil, unsigned* __restrict__ packA,
                             unsigned* __restrict__ packB, float* __restrict__ norm_s, int e) {
    int i = blockIdx.x * blockDim.x + threadIdx.x;
    if (i >= e) return;
    int d = dst[i];
    int p = off[d] + atomicAdd(&fil[d], 1);
    unsigned rhi = (unsigned)rel[i] << 16;
    int s = src[i];
    packA[p] = (unsigned)h_ids[s] | rhi;
    packB[p] = (unsigned)s | rhi;
    norm_s[p] = norm[i];
}

// fused conversion: w1,w2 -> f16 ; emb -> bf16
__global__ void cvt_all(const float* __restrict__ w1, const float* __restrict__ w2,
                        const float* __restrict__ emb, unsigned short* __restrict__ w1h,
                        unsigned short* __restrict__ w2h, unsigned short* __restrict__ embh,
                        int n1, int n2, int ne) {
    int i = blockIdx.x * blockDim.x + threadIdx.x;
    if (i < n1) w1h[i] = f2h(w1[i]);
    else if (i < n1 + n2) w2h[i - n1] = f2h(w2[i - n1]);
    else if (i < n1 + n2 + ne) embh[i - n1 - n2] = f2bf(emb[i - n1 - n2]);
}

// gemm1: h1bh[16-row tile] = bf16(b1 + embh[h_ids[row]] @ bf16(lw1))   (MFMA)
__global__ __launch_bounds__(256) void
gemm1_mfma(const unsigned short* __restrict__ embh, const int* __restrict__ h_ids,
           const float* __restrict__ lw1, const float* __restrict__ b1,
           unsigned short* __restrict__ h1bh, int n_nodes) {
    int w = threadIdx.x >> 6, l = threadIdx.x & 63;
    int lr = l & 15, lq = l >> 4;
    int rt = blockIdx.x;
    bf16x8 bfr[2];
    int coln = w * 16 + lr;
#pragma unroll
    for (int kb = 0; kb < 2; ++kb)
#pragma unroll
        for (int jj = 0; jj < 8; ++jj)
            bfr[kb][jj] = (short)f2bf(lw1[(kb * 32 + lq * 8 + jj) * 64 + coln]);
    int nrow = rt * 16 + lr;
    if (nrow >= n_nodes) nrow = n_nodes - 1;
    const unsigned short* arow = embh + (long)h_ids[nrow] * 64 + lq * 8;
    bf16x8 af0 = *(const bf16x8*)arow;
    bf16x8 af1 = *(const bf16x8*)(arow + 32);
    f32x4 acc = {0.f, 0.f, 0.f, 0.f};
    acc = __builtin_amdgcn_mfma_f32_16x16x32_bf16(af0, bfr[0], acc, 0, 0, 0);
    acc = __builtin_amdgcn_mfma_f32_16x16x32_bf16(af1, bfr[1], acc, 0, 0, 0);
    float bb = b1[coln];
#pragma unroll
    for (int r = 0; r < 4; ++r) {
        int row = rt * 16 + lq * 4 + r;
        if (row < n_nodes) h1bh[(long)row * 64 + coln] = f2bf(acc[r] + bb);
    }
}

// gemm2: h2bh[16-row tile] = bf16(b2 + h1h @ bf16(lw2))  (MFMA)
__global__ __launch_bounds__(256) void
gemm2_mfma(const unsigned short* __restrict__ h1h, const float* __restrict__ lw2,
           const float* __restrict__ b2, unsigned short* __restrict__ h2bh, int n_nodes) {
    int w = threadIdx.x >> 6, l = threadIdx.x & 63;
    int lr = l & 15, lq = l >> 4;
    int rt = blockIdx.x;
    bf16x8 bfr[2][2];
    int col0 = (2 * w) * 16 + lr, col1 = (2 * w + 1) * 16 + lr;
#pragma unroll
    for (int kb = 0; kb < 2; ++kb)
#pragma unroll
        for (int jj = 0; jj < 8; ++jj) {
            int k = kb * 32 + lq * 8 + jj;
            bfr[0][kb][jj] = (short)f2bf(lw2[k * 128 + col0]);
            bfr[1][kb][jj] = (short)f2bf(lw2[k * 128 + col1]);
        }
    int nrow = rt * 16 + lr;
    if (nrow >= n_nodes) nrow = n_nodes - 1;
    bf16x8 af0 = *(const bf16x8*)(h1h + (long)nrow * 64 + lq * 8);
    bf16x8 af1 = *(const bf16x8*)(h1h + (long)nrow * 64 + 32 + lq * 8);
    f32x4 acc0 = {0.f, 0.f, 0.f, 0.f}, acc1 = {0.f, 0.f, 0.f, 0.f};
    acc0 = __builtin_amdgcn_mfma_f32_16x16x32_bf16(af0, bfr[0][0], acc0, 0, 0, 0);
    acc0 = __builtin_amdgcn_mfma_f32_16x16x32_bf16(af1, bfr[0][1], acc0, 0, 0, 0);
    acc1 = __builtin_amdgcn_mfma_f32_16x16x32_bf16(af0, bfr[1][0], acc1, 0, 0, 0);
    acc1 = __builtin_amdgcn_mfma_f32_16x16x32_bf16(af1, bfr[1][1], acc1, 0, 0, 0);
    float bb0 = b2[col0], bb1 = b2[col1];
#pragma unroll
    for (int r = 0; r < 4; ++r) {
        int row = rt * 16 + lq * 4 + r;
        if (row < n_nodes) {
            h2bh[(long)row * 128 + col0] = f2bf(acc0[r] + bb0);
            h2bh[(long)row * 128 + col1] = f2bf(acc1[r] + bb1);
        }
    }
}

// butterfly transpose-reduce over 8-lane group
__device__ __forceinline__ float reduce8(float a0, float a1, float a2, float a3,
                                         float a4, float a5, float a6, float a7, int i) {
    int p1 = i & 1, p2 = (i >> 1) & 1, p3 = (i >> 2) & 1;
    float ka, sb, u0, u1, u2, u3, w0, w1;
    ka = p1 ? a1 : a0; sb = p1 ? a0 : a1; u0 = ka + __shfl_xor(sb, 1, 64);
    ka = p1 ? a3 : a2; sb = p1 ? a2 : a3; u1 = ka + __shfl_xor(sb, 1, 64);
    ka = p1 ? a5 : a4; sb = p1 ? a4 : a5; u2 = ka + __shfl_xor(sb, 1, 64);
    ka = p1 ? a7 : a6; sb = p1 ? a6 : a7; u3 = ka + __shfl_xor(sb, 1, 64);
    ka = p2 ? u1 : u0; sb = p2 ? u0 : u1; w0 = ka + __shfl_xor(sb, 2, 64);
    ka = p2 ? u3 : u2; sb = p2 ? u2 : u3; w1 = ka + __shfl_xor(sb, 2, 64);
    ka = p3 ? w1 : w0; sb = p3 ? w0 : w1;
    return ka + __shfl_xor(sb, 4, 64);
}

// edge1: h1h[n] = bf16(relu(h1bh[n] + sum_e nm * bdd(embh[pkA], w1h[rel])))
// one node per wave; source rows staged HBM->LDS via global_load_lds
__global__ __launch_bounds__(256) void
edge1(const unsigned short* __restrict__ embh, const unsigned short* __restrict__ w1h,
      const unsigned short* __restrict__ h1bh, const int* __restrict__ off,
      const unsigned* __restrict__ packA, const float* __restrict__ norm_s,
      unsigned short* __restrict__ h1h, int n_nodes) {
    __shared__ unsigned short xstage[4][8][64];   // 1KB per wave
    int tid = threadIdx.x;
    int w = tid >> 6, j = tid & 63, i = j & 7;
    int cl = j >> 3, il = j & 7;                  // lane -> (edge cl, 16B chunk il)
    int n = blockIdx.x * 4 + w;
    if (n >= n_nodes) return;
    unsigned short* xsw = &xstage[w][0][0];
    float base = bfs(h1bh[(long)n * 64 + j]);     // issue early
    h2 acc[4];
#pragma unroll
    for (int q = 0; q < 4; ++q) acc[q] = (h2){(_Float16)0.f, (_Float16)0.f};
    int e0 = off[n], e1v = off[n + 1];
    const long woff = (long)j * 8;
    for (int win = e0; win < e1v; win += 64) {
        int wcnt = e1v - win; if (wcnt > 64) wcnt = 64;
        unsigned u = (j < wcnt) ? packA[win + j] : 0u;
        float nmv = (j < wcnt) ? norm_s[win + j] : 0.f;
        for (int b8 = 0; b8 < wcnt; b8 += 8) {
            int cnt = wcnt - b8; if (cnt > 8) cnt = 8;
            int uc = __builtin_amdgcn_ds_bpermute((b8 + cl) << 2, (int)u);
            if (cl < cnt)   // lane j -> LDS byte j*16 (HW: base + lane*16)
                gload_lds16(embh + (long)((unsigned)uc & 0xFFFFu) * 64 + (il << 3), xsw);
            asm volatile("s_waitcnt vmcnt(0)" ::: "memory");
            __builtin_amdgcn_sched_barrier(0);
#pragma unroll
            for (int c = 0; c < 8; ++c)
                if (c < cnt) {
                    float nm = bcastf(nmv, b8 + c);
                    int rr = bcasti((int)u, b8 + c) >> 16;
                    uint4 wd = *(const uint4*)(w1h + (long)rr * 512 + woff);
                    _Float16 xh = (_Float16)(bfs(xsw[(c << 6) + j]) * nm);
                    h2 xh2 = {xh, xh};
                    acc[0] += xh2 * uh2(wd.x);
                    acc[1] += xh2 * uh2(wd.y);
                    acc[2] += xh2 * uh2(wd.z);
                    acc[3] += xh2 * uh2(wd.w);
                }
        }
    }
    float agg = reduce8((float)acc[0].x, (float)acc[0].y, (float)acc[1].x, (float)acc[1].y,
                        (float)acc[2].x, (float)acc[2].y, (float)acc[3].x, (float)acc[3].y, i);
    h1h[(long)n * 64 + j] = f2bf(fmaxf(base + agg, 0.f));
}

// edge2: out = reparam(h2bh[n] + sum_e nm * bdd(h1h[src], w2h[rel]))
__global__ __launch_bounds__(256) void
edge2(const unsigned short* __restrict__ h1h, const unsigned short* __restrict__ w2h,
      const unsigned short* __restrict__ h2bh, const float* __restrict__ eps,
      const int* __restrict__ off, const unsigned* __restrict__ packB,
      const float* __restrict__ norm_s, float* __restrict__ out, int n_nodes) {
    __shared__ unsigned short xstage[4][8][64];   // 1KB per wave
    int tid = threadIdx.x;
    int w = tid >> 6, j = tid & 63;
    int i = j & 7, b = j >> 3;
    int o1 = b * 16 + i, o2 = o1 + 8;
    int cl = j >> 3, il = j & 7;
    int n = blockIdx.x * 4 + w;
    if (n >= n_nodes) return;
    unsigned short* xsw = &xstage[w][0][0];
    float base1 = bfs(h2bh[(long)n * 128 + o1]);  // issue early
    float base2 = bfs(h2bh[(long)n * 128 + o2]);
    h2 acc[8];
#pragma unroll
    for (int q = 0; q < 8; ++q) acc[q] = (h2){(_Float16)0.f, (_Float16)0.f};
    int e0 = off[n], e1v = off[n + 1];
    const long woff = (long)j * 16;
    for (int win = e0; win < e1v; win += 64) {
        int wcnt = e1v - win; if (wcnt > 64) wcnt = 64;
        unsigned u = (j < wcnt) ? packB[win + j] : 0u;
        float nmv = (j < wcnt) ? norm_s[win + j] : 0.f;
        for (int b8 = 0; b8 < wcnt; b8 += 8) {
            int cnt = wcnt - b8; if (cnt > 8) cnt = 8;
            int uc = __builtin_amdgcn_ds_bpermute((b8 + cl) << 2, (int)u);
            if (cl < cnt)
                gload_lds16(h1h + (long)((unsigned)uc & 0xFFFFu) * 64 + (il << 3), xsw);
            asm volatile("s_waitcnt vmcnt(0)" ::: "memory");
            __builtin_amdgcn_sched_barrier(0);
#pragma unroll
            for (int c = 0; c < 8; ++c)
                if (c < cnt) {
                    float nm = bcastf(nmv, b8 + c);
                    int rr = bcasti((int)u, b8 + c) >> 16;
                    const uint4* p = (const uint4*)(w2h + (long)rr * 1024 + woff);
                    uint4 wa = p[0], wb = p[1];
                    _Float16 xh = (_Float16)(bfs(xsw[(c << 6) + j]) * nm);
                    h2 xh2 = {xh, xh};
                    acc[0] += xh2 * uh2(wa.x);
                    acc[1] += xh2 * uh2(wa.y);
                    acc[2] += xh2 * uh2(wa.z);
                    acc[3] += xh2 * uh2(wa.w);
                    acc[4] += xh2 * uh2(wb.x);
                    acc[5] += xh2 * uh2(wb.y);
                    acc[6] += xh2 * uh2(wb.z);
                    acc[7] += xh2 * uh2(wb.w);
                }
        }
    }
    float r1 = reduce8((float)acc[0].x, (float)acc[0].y, (float)acc[1].x, (float)acc[1].y,
                       (float)acc[2].x, (float)acc[2].y, (float)acc[3].x, (float)acc[3].y, i);
    float r2 = reduce8((float)acc[4].x, (float)acc[4].y, (float)acc[5].x, (float)acc[5].y,
                       (float)acc[6].x, (float)acc[6].y, (float)acc[7].x, (float)acc[7].y, i);
    float v1 = r1 + base1;
    float v2 = r2 + base2;
    float p1 = __shfl_xor(v1, 32, 64);
    float p2 = __shfl_xor(v2, 32, 64);
    if (j < 32) {
        long basep = (long)n * 64;
        float sp1 = (p1 > 20.f) ? p1 : log1pf(expf(p1));
        float sp2 = (p2 > 20.f) ? p2 : log1pf(expf(p2));
        out[basep + o1] = fmaf(sqrtf(sp1 + 1e-8f), eps[basep + o1], v1);
        out[basep + o2] = fmaf(sqrtf(sp2 + 1e-8f), eps[basep + o2], v2);
    }
}

extern "C" void kernel_launch(void* const* d_in, const int* in_sizes, int n_in,
                              void* d_out, int out_size, void* d_ws, size_t ws_size,
                              hipStream_t stream) {
    const float* emb   = (const float*)d_in[0];
    const float* norm  = (const float*)d_in[1];
    const float* eps   = (const float*)d_in[2];
    const float* w1    = (const float*)d_in[3];
    const float* lw1   = (const float*)d_in[4];
    const float* b1    = (const float*)d_in[5];
    const float* w2    = (const float*)d_in[6];
    const float* lw2   = (const float*)d_in[7];
    const float* b2    = (const float*)d_in[8];
    const int*   h_ids = (const int*)d_in[9];
    const int*   src   = (const int*)d_in[10];
    const int*   dst   = (const int*)d_in[11];
    const int*   rel   = (const int*)d_in[12];
    float* out = (float*)d_out;

    int n_nodes = in_sizes[0] / 64;   // 50000
    int n_edges = in_sizes[10];       // 400000
    int nw1 = in_sizes[3];            // 200*512
    int nw2 = in_sizes[6];            // 200*1024
    int ne  = in_sizes[0];            // N*64

    char* ws = (char*)d_ws;
    unsigned short* h1bh = (unsigned short*)ws;       ws += (size_t)n_nodes * 64 * 2;
    unsigned short* h1h  = (unsigned short*)ws;       ws += (size_t)n_nodes * 64 * 2;
    unsigned short* h2bh = (unsigned short*)ws;       ws += (size_t)n_nodes * 128 * 2;
    unsigned short* embh = (unsigned short*)ws;       ws += (size_t)ne * 2;
    unsigned short* w1h  = (unsigned short*)ws;       ws += (size_t)nw1 * 2;
    unsigned short* w2h  = (unsigned short*)ws;       ws += (size_t)nw2 * 2;
    unsigned* pkA = (unsigned*)ws;                    ws += (size_t)n_edges * 4;
    unsigned* pkB = (unsigned*)ws;                    ws += (size_t)n_edges * 4;
    float* norm_s = (float*)ws;                       ws += (size_t)n_edges * 4;
    int*   deg    = (int*)ws;                         ws += (size_t)n_nodes * 4;
    int*   fil    = (int*)ws;                         ws += (size_t)n_nodes * 4;
    int*   off    = (int*)ws;                         ws += (size_t)(n_nodes + 1) * 4;
    int*   bsum   = (int*)ws;

    int blk = 256;
    int nb = (n_nodes + 255) / 256;
    int nt = (n_nodes + 15) / 16;
    int ng = (n_nodes + 3) / 4;       // one node per wave
    // CSR build + conversions
    hipMemsetAsync(deg, 0, (size_t)n_nodes * 8, stream);
    cvt_all<<<(nw1 + nw2 + ne + blk - 1) / blk, blk, 0, stream>>>(w1, w2, emb, w1h, w2h, embh, nw1, nw2, ne);
    hist<<<(n_edges + blk - 1) / blk, blk, 0, stream>>>(dst, deg, n_edges);
    scan_part<<<nb, 256, 0, stream>>>(deg, bsum, n_nodes);
    scan_bsum<<<1, 256, 0, stream>>>(bsum, off, nb, n_nodes);
    scan_write<<<nb, 256, 0, stream>>>(deg, bsum, off, n_nodes);
    scatter_pack<<<(n_edges + blk - 1) / blk, blk, 0, stream>>>(src, dst, rel, norm, h_ids, off, fil, pkA, pkB, norm_s, n_edges);
    // layer 1
    gemm1_mfma<<<nt, blk, 0, stream>>>(embh, h_ids, lw1, b1, h1bh, n_nodes);
    edge1<<<ng, blk, 0, stream>>>(embh, w1h, h1bh, off, pkA, norm_s, h1h, n_nodes);
    // layer 2
    gemm2_mfma<<<nt, blk, 0, stream>>>(h1h, lw2, b2, h2bh, n_nodes);
    edge2<<<ng, blk, 0, stream>>>(h1h, w2h, h2bh, eps, off, pkB, norm_s, out, n_nodes);
}